// Round 2
// baseline (100.794 us; speedup 1.0000x reference)
//
#include <hip/hip_runtime.h>

#define IMG    256
#define NPIX   (IMG * IMG)          // 65536
#define NBATCH 64
#define NV     182                  // floor(sqrt(128^2+128^2)) + 1
#define NPROF  (NBATCH * NV)        // 11648

// ---- compile-time radial bin counts (validated R6/R7: absmax 0.0) ----
struct NbinTable { float inv[NV]; };

constexpr NbinTable make_table() {
    NbinTable t{};
    int cnt[NV] = {};
    for (int a = 0; a <= 128; ++a) {
        const int ma = (a == 0 || a == 128) ? 1 : 2;
        int r = a;
        for (int b = 0; b <= 128; ++b) {
            const int mb = (b == 0 || b == 128) ? 1 : 2;
            const int i2 = a * a + b * b;
            while ((r + 1) * (r + 1) <= i2) ++r;
            cnt[r] += ma * mb;
        }
    }
    for (int i = 0; i < NV; ++i) t.inv[i] = cnt[i] ? 1.0f / (float)cnt[i] : 0.0f;
    return t;
}

__constant__ NbinTable g_tab = make_table();

#define ELEM4(w, k) (((const float*)&(w))[(k)])

// Exact integer sqrt bin index (validated R3-R7 fixup sequence).
__device__ __forceinline__ int rbin(int i2) {
    int r = (int)sqrtf((float)i2);
    r += ((r + 1) * (r + 1) <= i2) ? 1 : 0;
    r -= (r * r > i2) ? 1 : 0;
    return r;
}

// One folded row-pair unit: thread handles left cols [4c..4c+3] and mirror
// cols [252-4c..255-4c] of row-pair q (rowT=q+1, rowB=255-q). Identical math
// to the validated R8 kernel, regrouped for the 1-block-per-batch layout.
__device__ __forceinline__ void bin_pair(const float* __restrict__ base,
                                         int q, int c, float* __restrict__ sbin)
{
    const int rowT = q + 1;            // 1..128
    const int rowB = 255 - q;          // 254..128
    const bool self = (q == 127);      // rowT == rowB == 128
    const int di  = rowT - 128;
    const int di2 = di * di;
    const int colL = 4 * c;            // left window base
    const int colM = 252 - 4 * c;      // mirror window base
    const int pTL = rowT * IMG + colL, pTM = rowT * IMG + colM;
    const int pBL = rowB * IMG + colL, pBM = rowB * IMG + colM;

    float4 TL[3], TM[3], BL[3], BM[3];
    const float4 z4 = {0.0f, 0.0f, 0.0f, 0.0f};
#pragma unroll
    for (int ch = 0; ch < 3; ++ch) {
        const float* p = base + ch * NPIX;
        TL[ch] = *(const float4*)(p + pTL);
        TM[ch] = *(const float4*)(p + pTM);
        if (!self) {
            BL[ch] = *(const float4*)(p + pBL);
            BM[ch] = *(const float4*)(p + pBM);
        } else { BL[ch] = z4; BM[ch] = z4; }
    }

    // row-folded lumas (x20 scale dropped: min-max normalize is scale-invariant)
    float vL[4], vM[4];
#pragma unroll
    for (int k = 0; k < 4; ++k) {
        vL[k] = 0.299f * (ELEM4(TL[0], k) + ELEM4(BL[0], k))
              + 0.587f * (ELEM4(TL[1], k) + ELEM4(BL[1], k))
              + 0.114f * (ELEM4(TL[2], k) + ELEM4(BL[2], k));
        vM[k] = 0.299f * (ELEM4(TM[0], k) + ELEM4(BM[0], k))
              + 0.587f * (ELEM4(TM[1], k) + ELEM4(BM[1], k))
              + 0.114f * (ELEM4(TM[2], k) + ELEM4(BM[2], k));
    }
    // column fold: mirror of col colL+k is mirror-window element 4-k
#pragma unroll
    for (int k = 1; k < 4; ++k) vL[k] += vM[4 - k];

    int rv[4];
#pragma unroll
    for (int k = 0; k < 4; ++k) {
        const int dj = colL + k - 128;
        rv[k] = rbin(di2 + dj * dj);
    }
    float acc = vL[0]; int rc = rv[0];
#pragma unroll
    for (int k = 1; k < 4; ++k) {
        if (rv[k] == rc) acc += vL[k];
        else { atomicAdd(&sbin[rc], acc); rc = rv[k]; acc = vL[k]; }
    }
    atomicAdd(&sbin[rc], acc);
    // leftover single: mirror-window base col
    {
        const int djm = 124 - 4 * c;              // colM - 128, in [0,124]
        atomicAdd(&sbin[rbin(di2 + djm * djm)], vM[0]);
    }
}

// One block per batch: full radial profile in LDS, plain-store to out.
// No workspace, no global atomics. grid = 64, block = 1024 (32 pairs x 32 c).
__global__ __launch_bounds__(1024) void radial_batch(const float* __restrict__ x,
                                                     float* __restrict__ out)  // [NBATCH][NV]
{
    __shared__ float sbin[NV];

    const int bt  = blockIdx.x;
    const int tid = threadIdx.x;
    const int lp  = tid >> 5;          // local pair 0..31
    const int c   = tid & 31;          // col group 0..31

    if (tid < NV) sbin[tid] = 0.0f;
    __syncthreads();

    const float* base = x + (size_t)bt * 3 * NPIX;

#pragma unroll
    for (int it = 0; it < 4; ++it)
        bin_pair(base, lp + 32 * it, c, sbin);

    // unpaired row 0 (di=-128): threads 0..31, same fold structure
    if (tid < 32) {
        const int c0 = tid, cl = 4 * c0, cm = 252 - 4 * c0;
        float4 L0[3], M0[3];
#pragma unroll
        for (int ch = 0; ch < 3; ++ch) {
            const float* p = base + ch * NPIX;
            L0[ch] = *(const float4*)(p + cl);
            M0[ch] = *(const float4*)(p + cm);
        }
        float vl[4], vm[4];
#pragma unroll
        for (int k = 0; k < 4; ++k) {
            vl[k] = 0.299f * ELEM4(L0[0], k) + 0.587f * ELEM4(L0[1], k) + 0.114f * ELEM4(L0[2], k);
            vm[k] = 0.299f * ELEM4(M0[0], k) + 0.587f * ELEM4(M0[1], k) + 0.114f * ELEM4(M0[2], k);
        }
#pragma unroll
        for (int k = 1; k < 4; ++k) vl[k] += vm[4 - k];
        int rv0[4];
#pragma unroll
        for (int k = 0; k < 4; ++k) {
            const int dj = cl + k - 128;
            rv0[k] = rbin(16384 + dj * dj);
        }
        float a0 = vl[0]; int r0 = rv0[0];
#pragma unroll
        for (int k = 1; k < 4; ++k) {
            if (rv0[k] == r0) a0 += vl[k];
            else { atomicAdd(&sbin[r0], a0); r0 = rv0[k]; a0 = vl[k]; }
        }
        atomicAdd(&sbin[r0], a0);
        const int djm = 124 - 4 * c0;
        atomicAdd(&sbin[rbin(16384 + djm * djm)], vm[0]);
    }
    __syncthreads();

    // unnormalized profile straight to out (overwrite; poison-immune)
    if (tid < NV) out[bt * NV + tid] = sbin[tid] * g_tab.inv[tid];
}

// Min-max normalize out in place. 1 x 1024. Each element read+written by the
// same thread; original values re-read after the barrier (L1/L2-hot).
__global__ __launch_bounds__(1024) void radial_norm(float* __restrict__ out) {
    __shared__ float smin[16], smax[16];
    const int tid = threadIdx.x;

    float mn = 3.4e38f, mx = -3.4e38f;
    for (int i = tid; i < NPROF; i += 1024) {
        const float p = out[i];
        mn = fminf(mn, p);
        mx = fmaxf(mx, p);
    }
#pragma unroll
    for (int off = 32; off > 0; off >>= 1) {
        mn = fminf(mn, __shfl_down(mn, off));
        mx = fmaxf(mx, __shfl_down(mx, off));
    }
    if ((tid & 63) == 0) { smin[tid >> 6] = mn; smax[tid >> 6] = mx; }
    __syncthreads();
    if (tid == 0) {
        float m1 = smin[0], m2 = smax[0];
        for (int w = 1; w < 16; ++w) {
            m1 = fminf(m1, smin[w]);
            m2 = fmaxf(m2, smax[w]);
        }
        smin[0] = m1; smax[0] = m2;
    }
    __syncthreads();

    const float mn_all = smin[0];
    const float inv = 1.0f / (smax[0] - mn_all);
    for (int i = tid; i < NPROF; i += 1024)
        out[i] = (out[i] - mn_all) * inv;
}

extern "C" void kernel_launch(void* const* d_in, const int* in_sizes, int n_in,
                              void* d_out, int out_size, void* d_ws, size_t ws_size,
                              hipStream_t stream) {
    const float* x = (const float*)d_in[0];
    float* out = (float*)d_out;
    (void)d_ws; (void)ws_size;   // workspace deliberately untouched

    radial_batch<<<dim3(NBATCH), 1024, 0, stream>>>(x, out);
    radial_norm<<<1, 1024, 0, stream>>>(out);
}